// Round 9
// baseline (731.114 us; speedup 1.0000x reference)
//
#include <hip/hip_runtime.h>
#include <hip/hip_bf16.h>

#define N_NODES 400000
#define N_EDGES 1600000
#define N_GRAPHS 16384
#define CHUNK 50
#define NCHUNK (N_NODES / CHUNK)   // 8000 chunks == one full resident generation
#define NCHUNKF (N_NODES / 64)     // 6250 fused-kernel chunks (64 nodes each)

#define BSHIFT 9
#define BKT_N (1 << BSHIFT)                               // 512 rows per bucket
#define NBKT ((N_NODES + BKT_N - 1) >> BSHIFT)            // 782 row-buckets
#define BIN_CHUNK 4096
#define NBBIN ((N_EDGES + BIN_CHUNK - 1) / BIN_CHUNK)     // 391

typedef __attribute__((ext_vector_type(8))) short bf16x8;
typedef __attribute__((ext_vector_type(4))) float f32x4;
typedef unsigned short bfu;

__device__ __forceinline__ float rlane(float x, int k) {
    return __int_as_float(__builtin_amdgcn_readlane(__float_as_int(x), k));
}
__device__ __forceinline__ int rlanei(int x, int k) {
    return __builtin_amdgcn_readlane(x, k);
}

__device__ __forceinline__ short f2bf(float x) {  // RNE float -> bf16 bits
    unsigned u = __float_as_uint(x);
    unsigned r = (u + 0x7fffu + ((u >> 16) & 1u)) >> 16;
    return (short)r;
}
__device__ __forceinline__ float bf2f(short b) {
    return __uint_as_float(((unsigned)(unsigned short)b) << 16);
}
__device__ __forceinline__ float bfu2f(bfu b) {
    return __uint_as_float(((unsigned)b) << 16);
}

// swizzled LDS address for [row][64 bfu] arrays: byte ^= (row&7)<<4.
// Spreads the stride-128B per-row pattern across 8 16B slots -> 2-way banks.
__device__ __forceinline__ bfu* sb_addr(bfu* base, int row, int col2) {
    int byte = ((row << 6) + col2) * 2;
    byte ^= (row & 7) << 4;
    return (bfu*)((char*)base + byte);
}

// ---- fused: bucket counts (blocks < NBBIN) + gstart boundary detect (all) ----
__global__ __launch_bounds__(256) void k_bcnt_gb(const int* __restrict__ rows,
                                                 int* __restrict__ bkt,
                                                 const int* __restrict__ batch,
                                                 int* __restrict__ gstart,
                                                 int N, int G, int E) {
    __shared__ int l[NBKT];
    const int t = threadIdx.x;
    const int b = blockIdx.x;
    int i = b * 256 + t;
    if (i <= N) {
        int bb = (i < N) ? batch[i] : G;
        int prev = (i == 0) ? -1 : batch[i - 1];
        for (int g = prev + 1; g <= bb; ++g) gstart[g] = i;
    }
    if (b < NBBIN) {
        for (int k = t; k < NBKT; k += 256) l[k] = 0;
        __syncthreads();
        const int e0 = b * BIN_CHUNK;
#pragma unroll
        for (int k = 0; k < 16; ++k) {
            int e = e0 + k * 256 + t;
            if (e < E) atomicAdd(&l[rows[e] >> BSHIFT], 1);
        }
        __syncthreads();
        for (int k = t; k < NBKT; k += 256)
            if (l[k]) atomicAdd(&bkt[k], l[k]);
    }
}

// ---- bin edges by row-bucket; per-block recomputed scan of bkt[] ----
__global__ __launch_bounds__(256) void k_bin(const int* __restrict__ rows,
                                             const int* __restrict__ cols,
                                             const int* __restrict__ bkt,
                                             int* __restrict__ bcur0,
                                             int2* __restrict__ tmp, int E) {
    __shared__ int lcnt[NBKT];
    __shared__ int gbase[NBKT];
    __shared__ int lbase[NBKT];
    __shared__ int tsum[256];
    const int t = threadIdx.x;
    for (int i = t; i < NBKT; i += 256) lcnt[i] = 0;
    __syncthreads();
    const int e0 = blockIdx.x * BIN_CHUNK;
    int r[16];
#pragma unroll
    for (int k = 0; k < 16; ++k) {
        int e = e0 + k * 256 + t;
        r[k] = (e < E) ? rows[e] : -1;
        if (r[k] >= 0) atomicAdd(&lcnt[r[k] >> BSHIFT], 1);
    }
    const int base4 = t * 4;
    int v[4];
    int run = 0;
#pragma unroll
    for (int k = 0; k < 4; ++k) {
        int idx = base4 + k;
        int x = (idx < NBKT) ? bkt[idx] : 0;
        v[k] = run;
        run += x;
    }
    tsum[t] = run;
    __syncthreads();
    for (int off = 1; off < 256; off <<= 1) {
        int x = (t >= off) ? tsum[t - off] : 0;
        __syncthreads();
        tsum[t] += x;
        __syncthreads();
    }
    const int texcl = tsum[t] - run;
#pragma unroll
    for (int k = 0; k < 4; ++k) {
        int idx = base4 + k;
        if (idx < NBKT) gbase[idx] = texcl + v[k];
    }
    __syncthreads();
    for (int i = t; i < NBKT; i += 256) {
        int c = lcnt[i];
        lbase[i] = c ? (gbase[i] + atomicAdd(&bcur0[i], c)) : 0;
    }
    __syncthreads();
    for (int i = t; i < NBKT; i += 256) lcnt[i] = 0;
    __syncthreads();
#pragma unroll
    for (int k = 0; k < 16; ++k) {
        if (r[k] >= 0) {
            int b = r[k] >> BSHIFT;
            int p = lbase[b] + atomicAdd(&lcnt[b], 1);
            tmp[p] = make_int2(r[k], cols[e0 + k * 256 + t]);
        }
    }
}

// ---- per-bucket CSR build; block computes its own base via reduction ----
__global__ __launch_bounds__(256) void k_csr(const int2* __restrict__ tmp,
                                             const int* __restrict__ bkt,
                                             int* __restrict__ row_ptr,
                                             float* __restrict__ dinv,
                                             int* __restrict__ colsOut,
                                             int N, int E) {
    __shared__ int lcnt[BKT_N];
    __shared__ int lofs[BKT_N];
    __shared__ int tsum[256];
    const int t = threadIdx.x;
    const int b = blockIdx.x;
    const int r0 = b << BSHIFT;
    int part = 0;
    for (int i = t; i < b; i += 256) part += bkt[i];
    tsum[t] = part;
    __syncthreads();
    for (int off = 128; off > 0; off >>= 1) {
        if (t < off) tsum[t] += tsum[t + off];
        __syncthreads();
    }
    const int S = tsum[0];
    const int T = S + bkt[b];
    __syncthreads();
    for (int i = t; i < BKT_N; i += 256) lcnt[i] = 0;
    __syncthreads();
    for (int e = S + t; e < T; e += 256) atomicAdd(&lcnt[tmp[e].x - r0], 1);
    __syncthreads();
    const int base2 = t * 2;
    int vals[2];
    int run = 0;
#pragma unroll
    for (int k = 0; k < 2; ++k) { vals[k] = run; run += lcnt[base2 + k]; }
    tsum[t] = run;
    __syncthreads();
    for (int off = 1; off < 256; off <<= 1) {
        int x = (t >= off) ? tsum[t - off] : 0;
        __syncthreads();
        tsum[t] += x;
        __syncthreads();
    }
    const int texcl = tsum[t] - run;
#pragma unroll
    for (int k = 0; k < 2; ++k) lofs[base2 + k] = texcl + vals[k];
    __syncthreads();
    for (int i = t; i < BKT_N; i += 256) {
        int node = r0 + i;
        if (node < N) {
            row_ptr[node] = S + lofs[i];
            dinv[node] = rsqrtf((float)lcnt[i] + 1.0f);
        }
    }
    if (b == 0 && t == 0) row_ptr[N] = E;
    __syncthreads();
    for (int e = S + t; e < T; e += 256) {
        int2 rc = tmp[e];
        int pos = S + atomicAdd(&lofs[rc.x - r0], 1);
        colsOut[pos] = rc.y;
    }
}

// ---- MFMA GEMM (grid-stride over 16-node tiles). ----
template <int IN_D, bool PRESCALE, bool ABF16>
__global__ __launch_bounds__(256, 4) void k_gemm_mfma(
        const void* __restrict__ in_, const float* __restrict__ W,
        const float* __restrict__ dinv, bfu* __restrict__ out, int nTiles) {
    constexpr int KT = IN_D / 32;
    const int lane = threadIdx.x & 63;
    const int m = lane & 15;
    const int q = lane >> 4;

    bf16x8 Bhi[4][KT], Blo[4][KT];
#pragma unroll
    for (int nt = 0; nt < 4; ++nt) {
#pragma unroll
        for (int kt = 0; kt < KT; ++kt) {
#pragma unroll
            for (int j = 0; j < 8; ++j) {
                int k = kt * 32 + q * 8 + j;
                float w = W[k * 64 + nt * 16 + m];
                short hi = f2bf(w);
                Bhi[nt][kt][j] = hi;
                Blo[nt][kt][j] = f2bf(w - bf2f(hi));
            }
        }
    }

    const int wv = (blockIdx.x * 256 + threadIdx.x) >> 6;
    const int nwv = (gridDim.x * 256) >> 6;

    for (int tile = wv; tile < nTiles; tile += nwv) {
        const int node0 = tile * 16;
        f32x4 C[4];
#pragma unroll
        for (int nt = 0; nt < 4; ++nt) C[nt] = (f32x4){0.f, 0.f, 0.f, 0.f};

        if (ABF16) {
            const bfu* rowb = (const bfu*)in_ + (size_t)(node0 + m) * IN_D + q * 8;
            bf16x8 A[KT];
#pragma unroll
            for (int kt = 0; kt < KT; ++kt) A[kt] = *(const bf16x8*)(rowb + kt * 32);
#pragma unroll
            for (int nt = 0; nt < 4; ++nt) {
#pragma unroll
                for (int kt = 0; kt < KT; ++kt) {
                    C[nt] = __builtin_amdgcn_mfma_f32_16x16x32_bf16(A[kt], Bhi[nt][kt], C[nt], 0, 0, 0);
                    C[nt] = __builtin_amdgcn_mfma_f32_16x16x32_bf16(A[kt], Blo[nt][kt], C[nt], 0, 0, 0);
                }
            }
        } else {
            const float dv = PRESCALE ? dinv[node0 + m] : 1.0f;
            const float* rowp = (const float*)in_ + (size_t)(node0 + m) * IN_D + q * 8;
            bf16x8 Ahi[KT], Alo[KT];
#pragma unroll
            for (int kt = 0; kt < KT; ++kt) {
                f32x4 a0 = *(const f32x4*)(rowp + kt * 32);
                f32x4 a1 = *(const f32x4*)(rowp + kt * 32 + 4);
#pragma unroll
                for (int j = 0; j < 4; ++j) {
                    float xx = PRESCALE ? dv * a0[j] : a0[j];
                    short hi = f2bf(xx);
                    Ahi[kt][j] = hi;
                    Alo[kt][j] = f2bf(xx - bf2f(hi));
                }
#pragma unroll
                for (int j = 0; j < 4; ++j) {
                    float xx = PRESCALE ? dv * a1[j] : a1[j];
                    short hi = f2bf(xx);
                    Ahi[kt][4 + j] = hi;
                    Alo[kt][4 + j] = f2bf(xx - bf2f(hi));
                }
            }
#pragma unroll
            for (int nt = 0; nt < 4; ++nt) {
#pragma unroll
                for (int kt = 0; kt < KT; ++kt) {
                    C[nt] = __builtin_amdgcn_mfma_f32_16x16x32_bf16(Ahi[kt], Bhi[nt][kt], C[nt], 0, 0, 0);
                    C[nt] = __builtin_amdgcn_mfma_f32_16x16x32_bf16(Ahi[kt], Blo[nt][kt], C[nt], 0, 0, 0);
                    C[nt] = __builtin_amdgcn_mfma_f32_16x16x32_bf16(Alo[kt], Bhi[nt][kt], C[nt], 0, 0, 0);
                }
            }
        }

        bfu* op = out + (size_t)node0 * 64;
#pragma unroll
        for (int nt = 0; nt < 4; ++nt) {
#pragma unroll
            for (int r = 0; r < 4; ++r) {
                op[(size_t)(q * 4 + r) * 64 + nt * 16 + m] = (bfu)f2bf(C[nt][r]);
            }
        }
    }
}

// ==== segmented-stream aggregation over bf16 M rows (layers 1, 3) ====
// Converged body (R7). POOL=0: out = bf16(d*relu(fmaf(d, self+acc, b))).
// POOL=1: relu pooled per graph-run -> atomics into psum/pmax.
template <int POOL>
__global__ __launch_bounds__(256, 8) void k_agg_seg(
        const bfu* __restrict__ M, const float* __restrict__ bias,
        const int* __restrict__ row_ptr, const int* __restrict__ cols,
        const float* __restrict__ dinv, const int* __restrict__ batch,
        bfu* __restrict__ out, float* __restrict__ psum,
        float* __restrict__ pmax) {
    const int lane = threadIdx.x & 63;
    int wid = (blockIdx.x * blockDim.x + threadIdx.x) >> 6;
    wid = __builtin_amdgcn_readfirstlane(wid);
    const int nw = (gridDim.x * blockDim.x) >> 6;
    const float b = bias[lane];
    const bfu* Ml = M + lane;

    for (int c = wid; c < NCHUNK; c += nw) {
        const int i0 = c * CHUNK;
        const int rpn = row_ptr[i0 + min(lane, CHUNK - 1) + 1];
        const int S = row_ptr[i0];
        const int ne = rlanei(rpn, CHUNK - 1) - S;
        const float dvv = dinv[i0 + min(lane, CHUNK - 1)];
        const int bvv = POOL ? batch[i0 + min(lane, CHUNK - 1)] : 0;

        int node = 0;
        int bnd = rlanei(rpn, 0) - S;
        float acc = 0.0f;
        float selfA = bfu2f(Ml[(size_t)i0 * 64]);
        float selfB = bfu2f(Ml[(size_t)(i0 + 1) * 64]);
        float selfC = bfu2f(Ml[(size_t)(i0 + 2) * 64]);
        int gcur = POOL ? rlanei(bvv, 0) : 0;
        float rsum = 0.0f, rmax = 0.0f;

        auto flush = [&]() {
            if (POOL) {
                atomicAdd(&psum[(size_t)gcur * 64 + lane], rsum);
                atomicMax((int*)&pmax[(size_t)gcur * 64 + lane], __float_as_int(rmax));
            }
        };
        auto finalize = [&]() {
            const float d = rlane(dvv, node);
            const float h = fmaxf(fmaf(d, selfA + acc, b), 0.0f);
            if (POOL) {
                const int g = rlanei(bvv, node);
                if (g != gcur) { flush(); gcur = g; rsum = 0.0f; rmax = 0.0f; }
                rsum += h;
                rmax = fmaxf(rmax, h);
            } else {
                out[(size_t)(i0 + node) * 64 + lane] = (bfu)f2bf(d * h);
            }
            acc = 0.0f;
            selfA = selfB;
            selfB = selfC;
            if (node + 3 < CHUNK) selfC = bfu2f(Ml[(size_t)(i0 + node + 3) * 64]);
            ++node;
            if (node < CHUNK) bnd = rlanei(rpn, node) - S;
        };

        if (ne > 0) {
            int bidx = 0;
            int a0 = S + lane, a1 = S + 64 + lane;
            int colv0 = (a0 < S + ne) ? cols[a0] : 0;
            int colv1 = (a1 < S + ne) ? cols[a1] : 0;
            unsigned ubuf[16];
#pragma unroll
            for (int k = 0; k < 16; ++k) {
                int e = min(k, ne - 1);
                int cc = rlanei(colv0, e);
                ubuf[k] = Ml[(size_t)cc * 64];
            }

            int j = 0;
            while (j + 16 <= ne) {
#pragma unroll
                for (int k = 0; k < 16; ++k) {
                    const int jj = j + k;
                    if ((jj & 63) == 0 && jj != 0) {
                        colv0 = colv1;
                        ++bidx;
                        int ad = S + (bidx + 1) * 64 + lane;
                        colv1 = (ad < S + ne) ? cols[ad] : 0;
                    }
                    while (jj == bnd) finalize();
                    acc += __uint_as_float(ubuf[k] << 16);
                    int ec = min(jj + 16, ne - 1);
                    int src = ((ec >> 6) == bidx) ? colv0 : colv1;
                    int cc = rlanei(src, ec & 63);
                    ubuf[k] = Ml[(size_t)cc * 64];
                }
                j += 16;
            }
            for (; j < ne; ++j) {
                while (j == bnd) finalize();
                acc += __uint_as_float(ubuf[j & 15] << 16);
            }
        }
        while (node < CHUNK) finalize();
        flush();
    }
}

// ==== fused layer-2: agg in h-space + in-wave MFMA GEMM + epilogue ====
// s_i = hb_i + sum_j hb_j (linearity: sum(h W) = (sum h) W). Stage s rows
// (bf16, XOR-swizzled) into a 32-row rotating per-wave LDS buffer; every 16
// finalized nodes fire a 16x64 @ 64x64 MFMA tile with W2 (hi/lo, transposed
// [col][k] in LDS), epilogue dinv*relu(dinv*C + b2), store bf16.
// Chunk = 64 nodes (lane-held metadata). Eliminates the GEMM2 dispatch and
// its 102 MB round-trip. Fire-catchups every 8 edges + tail/drain prevent
// the rotating-buffer overwrite hazard from empty-row chains.
__global__ __launch_bounds__(256, 5) void k_agg_gemm(
        const bfu* __restrict__ M, const float* __restrict__ W,
        const float* __restrict__ bias, const int* __restrict__ row_ptr,
        const int* __restrict__ cols, const float* __restrict__ dinv,
        bfu* __restrict__ out) {
    __shared__ bfu Wth[64 * 64];
    __shared__ bfu Wtl[64 * 64];
    __shared__ bfu Sb[4][32 * 64];
    const int t = threadIdx.x;
    const int lane = t & 63;
    const int m = lane & 15;
    const int q = lane >> 4;
    const int wvx = t >> 6;
    bfu* Sw = &Sb[wvx][0];

    // stage W transposed hi/lo: Wt[col][k], swizzled
    for (int idx = t; idx < 4096; idx += 256) {
        int kk = idx & 63, col = idx >> 6;
        float w = W[(size_t)kk * 64 + col];
        short hi = f2bf(w);
        *sb_addr(Wth, col, kk) = (bfu)hi;
        *sb_addr(Wtl, col, kk) = (bfu)f2bf(w - bf2f(hi));
    }
    __syncthreads();

    float b2r[4];
#pragma unroll
    for (int nt = 0; nt < 4; ++nt) b2r[nt] = bias[nt * 16 + m];

    int wid = (blockIdx.x * 256 + t) >> 6;
    wid = __builtin_amdgcn_readfirstlane(wid);
    const int nw = (gridDim.x * 256) >> 6;
    const bfu* Ml = M + lane;

    for (int c = wid; c < NCHUNKF; c += nw) {
        const int i0 = c * 64;
        const int rpn = row_ptr[i0 + lane + 1];
        const int S = row_ptr[i0];
        const int ne = rlanei(rpn, 63) - S;
        const float dvv = dinv[i0 + lane];

        int node = 0;
        int fired = 0;
        int bnd = rlanei(rpn, 0) - S;
        float acc = 0.0f;
        float selfA = bfu2f(Ml[(size_t)i0 * 64]);
        float selfB = bfu2f(Ml[(size_t)(i0 + 1) * 64]);
        float selfC = bfu2f(Ml[(size_t)(i0 + 2) * 64]);

        auto finalize = [&]() {
            *sb_addr(Sw, node & 31, lane) = (bfu)f2bf(selfA + acc);
            acc = 0.0f;
            selfA = selfB;
            selfB = selfC;
            if (node + 3 < 64) selfC = bfu2f(Ml[(size_t)(i0 + node + 3) * 64]);
            ++node;
            if (node < 64) bnd = rlanei(rpn, node) - S;
        };
        auto fire = [&](int t0) {
            f32x4 C[4];
#pragma unroll
            for (int nt = 0; nt < 4; ++nt) C[nt] = (f32x4){0.f, 0.f, 0.f, 0.f};
            const int brow = (t0 & 31) + m;
            bf16x8 A0 = *(const bf16x8*)sb_addr(Sw, brow, q * 8);
            bf16x8 A1 = *(const bf16x8*)sb_addr(Sw, brow, 32 + q * 8);
#pragma unroll
            for (int nt = 0; nt < 4; ++nt) {
                const int wcol = nt * 16 + m;
                bf16x8 Bh0 = *(const bf16x8*)sb_addr(Wth, wcol, q * 8);
                bf16x8 Bl0 = *(const bf16x8*)sb_addr(Wtl, wcol, q * 8);
                bf16x8 Bh1 = *(const bf16x8*)sb_addr(Wth, wcol, 32 + q * 8);
                bf16x8 Bl1 = *(const bf16x8*)sb_addr(Wtl, wcol, 32 + q * 8);
                C[nt] = __builtin_amdgcn_mfma_f32_16x16x32_bf16(A0, Bh0, C[nt], 0, 0, 0);
                C[nt] = __builtin_amdgcn_mfma_f32_16x16x32_bf16(A0, Bl0, C[nt], 0, 0, 0);
                C[nt] = __builtin_amdgcn_mfma_f32_16x16x32_bf16(A1, Bh1, C[nt], 0, 0, 0);
                C[nt] = __builtin_amdgcn_mfma_f32_16x16x32_bf16(A1, Bl1, C[nt], 0, 0, 0);
            }
            float dr[4];
#pragma unroll
            for (int r = 0; r < 4; ++r) dr[r] = __shfl(dvv, t0 + q * 4 + r);
#pragma unroll
            for (int nt = 0; nt < 4; ++nt) {
#pragma unroll
                for (int r = 0; r < 4; ++r) {
                    const int row = t0 + q * 4 + r;
                    float h = fmaxf(fmaf(dr[r], C[nt][r], b2r[nt]), 0.0f);
                    out[(size_t)(i0 + row) * 64 + nt * 16 + m] = (bfu)f2bf(dr[r] * h);
                }
            }
        };

        if (ne > 0) {
            int bidx = 0;
            int a0 = S + lane, a1 = S + 64 + lane;
            int colv0 = (a0 < S + ne) ? cols[a0] : 0;
            int colv1 = (a1 < S + ne) ? cols[a1] : 0;
            unsigned ubuf[16];
#pragma unroll
            for (int k = 0; k < 16; ++k) {
                int e = min(k, ne - 1);
                int cc = rlanei(colv0, e);
                ubuf[k] = Ml[(size_t)cc * 64];
            }

            int j = 0;
            while (j + 16 <= ne) {
#pragma unroll
                for (int k = 0; k < 8; ++k) {
                    const int jj = j + k;
                    if ((jj & 63) == 0 && jj != 0) {
                        colv0 = colv1;
                        ++bidx;
                        int ad = S + (bidx + 1) * 64 + lane;
                        colv1 = (ad < S + ne) ? cols[ad] : 0;
                    }
                    while (jj == bnd) finalize();
                    acc += __uint_as_float(ubuf[k] << 16);
                    int ec = min(jj + 16, ne - 1);
                    int src = ((ec >> 6) == bidx) ? colv0 : colv1;
                    int cc = rlanei(src, ec & 63);
                    ubuf[k] = Ml[(size_t)cc * 64];
                }
                while (node - fired >= 16) { fire(fired); fired += 16; }
#pragma unroll
                for (int k = 8; k < 16; ++k) {
                    const int jj = j + k;
                    if ((jj & 63) == 0 && jj != 0) {
                        colv0 = colv1;
                        ++bidx;
                        int ad = S + (bidx + 1) * 64 + lane;
                        colv1 = (ad < S + ne) ? cols[ad] : 0;
                    }
                    while (jj == bnd) finalize();
                    acc += __uint_as_float(ubuf[k] << 16);
                    int ec = min(jj + 16, ne - 1);
                    int src = ((ec >> 6) == bidx) ? colv0 : colv1;
                    int cc = rlanei(src, ec & 63);
                    ubuf[k] = Ml[(size_t)cc * 64];
                }
                while (node - fired >= 16) { fire(fired); fired += 16; }
                j += 16;
            }
            for (; j < ne; ++j) {
                while (j == bnd) finalize();
                while (node - fired >= 16) { fire(fired); fired += 16; }
                acc += __uint_as_float(ubuf[j & 15] << 16);
            }
        }
        while (node < 64) {
            finalize();
            while (node - fired >= 16) { fire(fired); fired += 16; }
        }
        while (fired < 64) { fire(fired); fired += 16; }
    }
}

// ---- assemble fused vector: [mean | max | relu(meta@Wm+bm) | emb | pad] ----
__global__ __launch_bounds__(256) void k_asm(
        const float* __restrict__ psum, const float* __restrict__ pmax,
        const int* __restrict__ gstart, const float* __restrict__ metadata,
        const int* __restrict__ species, const float* __restrict__ emb,
        const float* __restrict__ Wm, const float* __restrict__ bm,
        float* __restrict__ fused, int G) {
    const int lane = threadIdx.x & 63;
    int wv = (blockIdx.x * blockDim.x + threadIdx.x) >> 6;
    const int nw = (gridDim.x * blockDim.x) >> 6;
    const float bmr = bm[lane];
    float wmr[16];
#pragma unroll
    for (int k = 0; k < 16; ++k) wmr[k] = Wm[k * 64 + lane];
    for (int g = wv; g < G; g += nw) {
        float gc = (float)(gstart[g + 1] - gstart[g]);
        float mean = psum[(size_t)g * 64 + lane] / fmaxf(gc, 1.0f);
        float mx = pmax[(size_t)g * 64 + lane];
        float md = lane < 16 ? metadata[(size_t)g * 16 + lane] : 0.0f;
        float mval = bmr;
#pragma unroll
        for (int k = 0; k < 16; ++k) mval = fmaf(rlane(md, k), wmr[k], mval);
        mval = fmaxf(mval, 0.0f);
        const int sid = species[g];
        float* fr = fused + (size_t)g * 224;
        fr[lane] = mean;
        fr[64 + lane] = mx;
        fr[128 + lane] = mval;
        if (lane < 16) fr[192 + lane] = emb[(size_t)sid * 16 + lane];
        else if (lane < 32) fr[192 + lane] = 0.0f;
    }
}

// ---- MFMA predictor head ----
__global__ __launch_bounds__(256, 2) void k_pred_mfma(
        const float* __restrict__ fused, const float* __restrict__ Wp1,
        const float* __restrict__ bp1, const float* __restrict__ Wp2,
        const float* __restrict__ bp2, float* __restrict__ out, int G) {
    __shared__ __align__(16) short Whi[64 * 232];
    __shared__ __align__(16) short Wlo[64 * 232];
    const int t = threadIdx.x;
    for (int idx = t; idx < 64 * 232; idx += 256) {
        int n = idx / 232;
        int k = idx % 232;
        float w = (k < 208) ? Wp1[(size_t)k * 64 + n] : 0.0f;
        short hi = f2bf(w);
        Whi[n * 232 + k] = hi;
        Wlo[n * 232 + k] = f2bf(w - bf2f(hi));
    }
    __syncthreads();

    const int lane = t & 63;
    const int wave = t >> 6;
    const int m = lane & 15;
    const int q = lane >> 4;
    const int g0 = (blockIdx.x * 4 + wave) * 16;
    if (g0 >= G) return;

    const float* rowp = fused + (size_t)(g0 + m) * 224 + q * 8;

    f32x4 C[4];
#pragma unroll
    for (int nt = 0; nt < 4; ++nt) C[nt] = (f32x4){0.f, 0.f, 0.f, 0.f};

#pragma unroll
    for (int kt = 0; kt < 7; ++kt) {
        f32x4 a0 = *(const f32x4*)(rowp + kt * 32);
        f32x4 a1 = *(const f32x4*)(rowp + kt * 32 + 4);
        bf16x8 Ahi, Alo;
#pragma unroll
        for (int j = 0; j < 4; ++j) {
            short hi = f2bf(a0[j]);
            Ahi[j] = hi;
            Alo[j] = f2bf(a0[j] - bf2f(hi));
        }
#pragma unroll
        for (int j = 0; j < 4; ++j) {
            short hi = f2bf(a1[j]);
            Ahi[4 + j] = hi;
            Alo[4 + j] = f2bf(a1[j] - bf2f(hi));
        }
#pragma unroll
        for (int nt = 0; nt < 4; ++nt) {
            const int boff = (nt * 16 + m) * 232 + kt * 32 + q * 8;
            bf16x8 Bh = *(const bf16x8*)&Whi[boff];
            bf16x8 Bl = *(const bf16x8*)&Wlo[boff];
            C[nt] = __builtin_amdgcn_mfma_f32_16x16x32_bf16(Ahi, Bh, C[nt], 0, 0, 0);
            C[nt] = __builtin_amdgcn_mfma_f32_16x16x32_bf16(Ahi, Bl, C[nt], 0, 0, 0);
            C[nt] = __builtin_amdgcn_mfma_f32_16x16x32_bf16(Alo, Bh, C[nt], 0, 0, 0);
        }
    }

    float wp2r[4], bp1r[4];
#pragma unroll
    for (int nt = 0; nt < 4; ++nt) {
        wp2r[nt] = Wp2[nt * 16 + m];
        bp1r[nt] = bp1[nt * 16 + m];
    }
    const float bp2v = bp2[0];
    float s[4];
#pragma unroll
    for (int r = 0; r < 4; ++r) {
        float acc = 0.0f;
#pragma unroll
        for (int nt = 0; nt < 4; ++nt)
            acc += fmaxf(C[nt][r] + bp1r[nt], 0.0f) * wp2r[nt];
        s[r] = acc;
    }
#pragma unroll
    for (int off = 1; off < 16; off <<= 1) {
#pragma unroll
        for (int r = 0; r < 4; ++r) s[r] += __shfl_xor(s[r], off);
    }
    if (m == 0) {
#pragma unroll
        for (int r = 0; r < 4; ++r) out[g0 + q * 4 + r] = s[r] + bp2v;
    }
}

extern "C" void kernel_launch(void* const* d_in, const int* in_sizes, int n_in,
                              void* d_out, int out_size, void* d_ws, size_t ws_size,
                              hipStream_t stream) {
    const int N = N_NODES, E = N_EDGES, G = N_GRAPHS;

    const float* x        = (const float*)d_in[0];
    const float* metadata = (const float*)d_in[1];
    const int*   ei       = (const int*)d_in[2];
    const int*   batch    = (const int*)d_in[3];
    const int*   species  = (const int*)d_in[4];
    const float* W1 = (const float*)d_in[5];
    const float* b1 = (const float*)d_in[6];
    const float* W2 = (const float*)d_in[7];
    const float* b2 = (const float*)d_in[8];
    const float* W3 = (const float*)d_in[9];
    const float* b3 = (const float*)d_in[10];
    const float* Wm = (const float*)d_in[11];
    const float* bm = (const float*)d_in[12];
    const float* emb = (const float*)d_in[13];
    const float* Wp1 = (const float*)d_in[14];
    const float* bp1 = (const float*)d_in[15];
    const float* Wp2 = (const float*)d_in[16];
    const float* bp2 = (const float*)d_in[17];
    float* out = (float*)d_out;

    char* ws = (char*)d_ws;
    size_t off = 0;
    auto alloc = [&](size_t bytes) -> void* {
        void* p = ws + off;
        off = (off + bytes + 255) & ~(size_t)255;
        return p;
    };
    int*   row_ptr = (int*)alloc((size_t)(N + 1) * 4);
    float* dinv    = (float*)alloc((size_t)N * 4);
    int*   gstart  = (int*)alloc((size_t)(G + 1) * 4);
    // ---- contiguous zero region: bkt | bcur | psum | pmax (single memset) ----
    size_t z0 = off;
    int*   bkt     = (int*)alloc((size_t)NBKT * 4);
    int*   bcur    = (int*)alloc((size_t)NBKT * 4);
    float* psum    = (float*)alloc((size_t)G * 64 * 4);
    float* pmax    = (float*)alloc((size_t)G * 64 * 4);
    size_t zlen = off - z0;
    // -------------------------------------------------------------------------
    int*   colsS   = (int*)alloc((size_t)E * 4);
    bfu*   Mb      = (bfu*)alloc((size_t)N * 64 * 2);
    bfu*   hb      = (bfu*)alloc((size_t)N * 64 * 2);
    float* fused   = (float*)alloc((size_t)G * 224 * 4);

    int2* tmp = (int2*)Mb;        // aliases Mb: dead until layer-1 GEMM writes it

    hipMemsetAsync(ws + z0, 0, zlen, stream);

    const int nbGb = (N + 256) / 256 + 1;                // 1563 >= NBBIN(391)
    k_bcnt_gb<<<nbGb, 256, 0, stream>>>(ei, bkt, batch, gstart, N, G, E);
    k_bin<<<NBBIN, 256, 0, stream>>>(ei, ei + E, bkt, bcur, tmp, E);
    k_csr<<<NBKT, 256, 0, stream>>>(tmp, bkt, row_ptr, dinv, colsS, N, E);

    const int nTiles = N / 16;          // 25000
    const int nbAgg = NCHUNK / 4;       // 2000 blocks = 8000 waves = NCHUNK
    const int nbF = (NCHUNKF + 3) / 4;  // 1563 blocks for fused layer-2
    // layer 1: M1 = (Dinv x) @ W1 (bf16) ; agg -> h1' bf16 (hb)
    k_gemm_mfma<32, true, false><<<1563, 256, 0, stream>>>(x, W1, dinv, Mb, nTiles);
    k_agg_seg<0><<<nbAgg, 256, 0, stream>>>(Mb, b1, row_ptr, colsS, dinv, batch,
                                            hb, psum, pmax);
    // layer 2 FUSED: gather hb, s = self+sum, sW2 via MFMA, epilogue -> Mb
    k_agg_gemm<<<nbF, 256, 0, stream>>>(hb, W2, b2, row_ptr, colsS, dinv, Mb);
    // layer 3: GEMM (A bf16, Mb -> hb = M3) then agg+pool
    k_gemm_mfma<64, false, true><<<1563, 256, 0, stream>>>(Mb, W3, dinv, hb, nTiles);
    k_agg_seg<1><<<nbAgg, 256, 0, stream>>>(hb, b3, row_ptr, colsS, dinv, batch,
                                            Mb, psum, pmax);

    k_asm<<<512, 256, 0, stream>>>(psum, pmax, gstart, metadata, species, emb, Wm, bm,
                                   fused, G);
    k_pred_mfma<<<(G / 16 + 3) / 4, 256, 0, stream>>>(fused, Wp1, bp1, Wp2, bp2, out, G);
}

// Round 10
// 467.097 us; speedup vs baseline: 1.5652x; 1.5652x over previous
//
#include <hip/hip_runtime.h>
#include <hip/hip_bf16.h>

#define N_NODES 400000
#define N_EDGES 1600000
#define N_GRAPHS 16384
#define CHUNK 50
#define NCHUNK (N_NODES / CHUNK)   // 8000 chunks == one full resident generation

#define BSHIFT 9
#define BKT_N (1 << BSHIFT)                               // 512 rows per bucket
#define NBKT ((N_NODES + BKT_N - 1) >> BSHIFT)            // 782 row-buckets
#define BIN_CHUNK 4096
#define NBBIN ((N_EDGES + BIN_CHUNK - 1) / BIN_CHUNK)     // 391

typedef __attribute__((ext_vector_type(8))) short bf16x8;
typedef __attribute__((ext_vector_type(4))) float f32x4;
typedef unsigned short bfu;

__device__ __forceinline__ float rlane(float x, int k) {
    return __int_as_float(__builtin_amdgcn_readlane(__float_as_int(x), k));
}
__device__ __forceinline__ int rlanei(int x, int k) {
    return __builtin_amdgcn_readlane(x, k);
}

__device__ __forceinline__ short f2bf(float x) {  // RNE float -> bf16 bits
    unsigned u = __float_as_uint(x);
    unsigned r = (u + 0x7fffu + ((u >> 16) & 1u)) >> 16;
    return (short)r;
}
__device__ __forceinline__ float bf2f(short b) {
    return __uint_as_float(((unsigned)(unsigned short)b) << 16);
}
__device__ __forceinline__ float bfu2f(bfu b) {
    return __uint_as_float(((unsigned)b) << 16);
}

// ---- fused: bucket counts (blocks < NBBIN) + gstart boundary detect (all) ----
__global__ __launch_bounds__(256) void k_bcnt_gb(const int* __restrict__ rows,
                                                 int* __restrict__ bkt,
                                                 const int* __restrict__ batch,
                                                 int* __restrict__ gstart,
                                                 int N, int G, int E) {
    __shared__ int l[NBKT];
    const int t = threadIdx.x;
    const int b = blockIdx.x;
    int i = b * 256 + t;
    if (i <= N) {
        int bb = (i < N) ? batch[i] : G;
        int prev = (i == 0) ? -1 : batch[i - 1];
        for (int g = prev + 1; g <= bb; ++g) gstart[g] = i;
    }
    if (b < NBBIN) {
        for (int k = t; k < NBKT; k += 256) l[k] = 0;
        __syncthreads();
        const int e0 = b * BIN_CHUNK;
#pragma unroll
        for (int k = 0; k < 16; ++k) {
            int e = e0 + k * 256 + t;
            if (e < E) atomicAdd(&l[rows[e] >> BSHIFT], 1);
        }
        __syncthreads();
        for (int k = t; k < NBKT; k += 256)
            if (l[k]) atomicAdd(&bkt[k], l[k]);
    }
}

// ---- bin edges by row-bucket; per-block recomputed scan of bkt[] ----
__global__ __launch_bounds__(256) void k_bin(const int* __restrict__ rows,
                                             const int* __restrict__ cols,
                                             const int* __restrict__ bkt,
                                             int* __restrict__ bcur0,
                                             int2* __restrict__ tmp, int E) {
    __shared__ int lcnt[NBKT];
    __shared__ int gbase[NBKT];
    __shared__ int lbase[NBKT];
    __shared__ int tsum[256];
    const int t = threadIdx.x;
    for (int i = t; i < NBKT; i += 256) lcnt[i] = 0;
    __syncthreads();
    const int e0 = blockIdx.x * BIN_CHUNK;
    int r[16];
#pragma unroll
    for (int k = 0; k < 16; ++k) {
        int e = e0 + k * 256 + t;
        r[k] = (e < E) ? rows[e] : -1;
        if (r[k] >= 0) atomicAdd(&lcnt[r[k] >> BSHIFT], 1);
    }
    const int base4 = t * 4;
    int v[4];
    int run = 0;
#pragma unroll
    for (int k = 0; k < 4; ++k) {
        int idx = base4 + k;
        int x = (idx < NBKT) ? bkt[idx] : 0;
        v[k] = run;
        run += x;
    }
    tsum[t] = run;
    __syncthreads();
    for (int off = 1; off < 256; off <<= 1) {
        int x = (t >= off) ? tsum[t - off] : 0;
        __syncthreads();
        tsum[t] += x;
        __syncthreads();
    }
    const int texcl = tsum[t] - run;
#pragma unroll
    for (int k = 0; k < 4; ++k) {
        int idx = base4 + k;
        if (idx < NBKT) gbase[idx] = texcl + v[k];
    }
    __syncthreads();
    for (int i = t; i < NBKT; i += 256) {
        int c = lcnt[i];
        lbase[i] = c ? (gbase[i] + atomicAdd(&bcur0[i], c)) : 0;
    }
    __syncthreads();
    for (int i = t; i < NBKT; i += 256) lcnt[i] = 0;
    __syncthreads();
#pragma unroll
    for (int k = 0; k < 16; ++k) {
        if (r[k] >= 0) {
            int b = r[k] >> BSHIFT;
            int p = lbase[b] + atomicAdd(&lcnt[b], 1);
            tmp[p] = make_int2(r[k], cols[e0 + k * 256 + t]);
        }
    }
}

// ---- per-bucket CSR build; block computes its own base via reduction ----
__global__ __launch_bounds__(256) void k_csr(const int2* __restrict__ tmp,
                                             const int* __restrict__ bkt,
                                             int* __restrict__ row_ptr,
                                             float* __restrict__ dinv,
                                             int* __restrict__ colsOut,
                                             int N, int E) {
    __shared__ int lcnt[BKT_N];
    __shared__ int lofs[BKT_N];
    __shared__ int tsum[256];
    const int t = threadIdx.x;
    const int b = blockIdx.x;
    const int r0 = b << BSHIFT;
    int part = 0;
    for (int i = t; i < b; i += 256) part += bkt[i];
    tsum[t] = part;
    __syncthreads();
    for (int off = 128; off > 0; off >>= 1) {
        if (t < off) tsum[t] += tsum[t + off];
        __syncthreads();
    }
    const int S = tsum[0];
    const int T = S + bkt[b];
    __syncthreads();
    for (int i = t; i < BKT_N; i += 256) lcnt[i] = 0;
    __syncthreads();
    for (int e = S + t; e < T; e += 256) atomicAdd(&lcnt[tmp[e].x - r0], 1);
    __syncthreads();
    const int base2 = t * 2;
    int vals[2];
    int run = 0;
#pragma unroll
    for (int k = 0; k < 2; ++k) { vals[k] = run; run += lcnt[base2 + k]; }
    tsum[t] = run;
    __syncthreads();
    for (int off = 1; off < 256; off <<= 1) {
        int x = (t >= off) ? tsum[t - off] : 0;
        __syncthreads();
        tsum[t] += x;
        __syncthreads();
    }
    const int texcl = tsum[t] - run;
#pragma unroll
    for (int k = 0; k < 2; ++k) lofs[base2 + k] = texcl + vals[k];
    __syncthreads();
    for (int i = t; i < BKT_N; i += 256) {
        int node = r0 + i;
        if (node < N) {
            row_ptr[node] = S + lofs[i];
            dinv[node] = rsqrtf((float)lcnt[i] + 1.0f);
        }
    }
    if (b == 0 && t == 0) row_ptr[N] = E;
    __syncthreads();
    for (int e = S + t; e < T; e += 256) {
        int2 rc = tmp[e];
        int pos = S + atomicAdd(&lofs[rc.x - r0], 1);
        colsOut[pos] = rc.y;
    }
}

// ---- MFMA GEMM (grid-stride over 16-node tiles). ----
// Grid = 1024 blocks: exactly 4 blocks/CU resident (launch_bounds cap), one
// generation, no tail; grid-stride loop covers all tiles.
template <int IN_D, bool PRESCALE, bool ABF16>
__global__ __launch_bounds__(256, 4) void k_gemm_mfma(
        const void* __restrict__ in_, const float* __restrict__ W,
        const float* __restrict__ dinv, bfu* __restrict__ out, int nTiles) {
    constexpr int KT = IN_D / 32;
    const int lane = threadIdx.x & 63;
    const int m = lane & 15;
    const int q = lane >> 4;

    bf16x8 Bhi[4][KT], Blo[4][KT];
#pragma unroll
    for (int nt = 0; nt < 4; ++nt) {
#pragma unroll
        for (int kt = 0; kt < KT; ++kt) {
#pragma unroll
            for (int j = 0; j < 8; ++j) {
                int k = kt * 32 + q * 8 + j;
                float w = W[k * 64 + nt * 16 + m];
                short hi = f2bf(w);
                Bhi[nt][kt][j] = hi;
                Blo[nt][kt][j] = f2bf(w - bf2f(hi));
            }
        }
    }

    const int wv = (blockIdx.x * 256 + threadIdx.x) >> 6;
    const int nwv = (gridDim.x * 256) >> 6;

    for (int tile = wv; tile < nTiles; tile += nwv) {
        const int node0 = tile * 16;
        f32x4 C[4];
#pragma unroll
        for (int nt = 0; nt < 4; ++nt) C[nt] = (f32x4){0.f, 0.f, 0.f, 0.f};

        if (ABF16) {
            const bfu* rowb = (const bfu*)in_ + (size_t)(node0 + m) * IN_D + q * 8;
            bf16x8 A[KT];
#pragma unroll
            for (int kt = 0; kt < KT; ++kt) A[kt] = *(const bf16x8*)(rowb + kt * 32);
#pragma unroll
            for (int nt = 0; nt < 4; ++nt) {
#pragma unroll
                for (int kt = 0; kt < KT; ++kt) {
                    C[nt] = __builtin_amdgcn_mfma_f32_16x16x32_bf16(A[kt], Bhi[nt][kt], C[nt], 0, 0, 0);
                    C[nt] = __builtin_amdgcn_mfma_f32_16x16x32_bf16(A[kt], Blo[nt][kt], C[nt], 0, 0, 0);
                }
            }
        } else {
            const float dv = PRESCALE ? dinv[node0 + m] : 1.0f;
            const float* rowp = (const float*)in_ + (size_t)(node0 + m) * IN_D + q * 8;
            bf16x8 Ahi[KT], Alo[KT];
#pragma unroll
            for (int kt = 0; kt < KT; ++kt) {
                f32x4 a0 = *(const f32x4*)(rowp + kt * 32);
                f32x4 a1 = *(const f32x4*)(rowp + kt * 32 + 4);
#pragma unroll
                for (int j = 0; j < 4; ++j) {
                    float xx = PRESCALE ? dv * a0[j] : a0[j];
                    short hi = f2bf(xx);
                    Ahi[kt][j] = hi;
                    Alo[kt][j] = f2bf(xx - bf2f(hi));
                }
#pragma unroll
                for (int j = 0; j < 4; ++j) {
                    float xx = PRESCALE ? dv * a1[j] : a1[j];
                    short hi = f2bf(xx);
                    Ahi[kt][4 + j] = hi;
                    Alo[kt][4 + j] = f2bf(xx - bf2f(hi));
                }
            }
#pragma unroll
            for (int nt = 0; nt < 4; ++nt) {
#pragma unroll
                for (int kt = 0; kt < KT; ++kt) {
                    C[nt] = __builtin_amdgcn_mfma_f32_16x16x32_bf16(Ahi[kt], Bhi[nt][kt], C[nt], 0, 0, 0);
                    C[nt] = __builtin_amdgcn_mfma_f32_16x16x32_bf16(Ahi[kt], Blo[nt][kt], C[nt], 0, 0, 0);
                    C[nt] = __builtin_amdgcn_mfma_f32_16x16x32_bf16(Alo[kt], Bhi[nt][kt], C[nt], 0, 0, 0);
                }
            }
        }

        bfu* op = out + (size_t)node0 * 64;
#pragma unroll
        for (int nt = 0; nt < 4; ++nt) {
#pragma unroll
            for (int r = 0; r < 4; ++r) {
                op[(size_t)(q * 4 + r) * 64 + nt * 16 + m] = (bfu)f2bf(C[nt][r]);
            }
        }
    }
}

// ==== segmented-stream aggregation over bf16 M rows ====
// Converged body (R7): 16-deep VGPR ring; col window in VGPRs + per-edge
// readlane [R3: no per-edge memory loads]; ring depth 16 [R4: 32 spills];
// static schedule [R5: atomic counter poison]; single stream [R2/R6];
// no gather+MFMA fusion [R9: spill catastrophe]; CHUNK=50 -> 8000 chunks
// = one resident generation.
// POOL=0: out[i] = bf16( dinv[i] * relu(dinv[i]*(M_i + sum_j M_j) + b) )
// POOL=1: h3 = relu(...) pooled per graph-run -> atomics into psum/pmax.
template <int POOL>
__global__ __launch_bounds__(256, 8) void k_agg_seg(
        const bfu* __restrict__ M, const float* __restrict__ bias,
        const int* __restrict__ row_ptr, const int* __restrict__ cols,
        const float* __restrict__ dinv, const int* __restrict__ batch,
        bfu* __restrict__ out, float* __restrict__ psum,
        float* __restrict__ pmax) {
    const int lane = threadIdx.x & 63;
    int wid = (blockIdx.x * blockDim.x + threadIdx.x) >> 6;
    wid = __builtin_amdgcn_readfirstlane(wid);
    const int nw = (gridDim.x * blockDim.x) >> 6;
    const float b = bias[lane];
    const bfu* Ml = M + lane;

    for (int c = wid; c < NCHUNK; c += nw) {
        const int i0 = c * CHUNK;
        const int rpn = row_ptr[i0 + min(lane, CHUNK - 1) + 1];
        const int S = row_ptr[i0];
        const int ne = rlanei(rpn, CHUNK - 1) - S;
        const float dvv = dinv[i0 + min(lane, CHUNK - 1)];
        const int bvv = POOL ? batch[i0 + min(lane, CHUNK - 1)] : 0;

        int node = 0;
        int bnd = rlanei(rpn, 0) - S;
        float acc = 0.0f;
        float selfA = bfu2f(Ml[(size_t)i0 * 64]);
        float selfB = bfu2f(Ml[(size_t)(i0 + 1) * 64]);
        float selfC = bfu2f(Ml[(size_t)(i0 + 2) * 64]);
        int gcur = POOL ? rlanei(bvv, 0) : 0;
        float rsum = 0.0f, rmax = 0.0f;

        auto flush = [&]() {
            if (POOL) {
                atomicAdd(&psum[(size_t)gcur * 64 + lane], rsum);
                atomicMax((int*)&pmax[(size_t)gcur * 64 + lane], __float_as_int(rmax));
            }
        };
        auto finalize = [&]() {
            const float d = rlane(dvv, node);
            const float h = fmaxf(fmaf(d, selfA + acc, b), 0.0f);
            if (POOL) {
                const int g = rlanei(bvv, node);
                if (g != gcur) { flush(); gcur = g; rsum = 0.0f; rmax = 0.0f; }
                rsum += h;
                rmax = fmaxf(rmax, h);
            } else {
                out[(size_t)(i0 + node) * 64 + lane] = (bfu)f2bf(d * h);
            }
            acc = 0.0f;
            selfA = selfB;
            selfB = selfC;
            if (node + 3 < CHUNK) selfC = bfu2f(Ml[(size_t)(i0 + node + 3) * 64]);
            ++node;
            if (node < CHUNK) bnd = rlanei(rpn, node) - S;
        };

        if (ne > 0) {
            int bidx = 0;
            int a0 = S + lane, a1 = S + 64 + lane;
            int colv0 = (a0 < S + ne) ? cols[a0] : 0;
            int colv1 = (a1 < S + ne) ? cols[a1] : 0;
            unsigned ubuf[16];
#pragma unroll
            for (int k = 0; k < 16; ++k) {
                int e = min(k, ne - 1);
                int cc = rlanei(colv0, e);
                ubuf[k] = Ml[(size_t)cc * 64];
            }

            int j = 0;
            while (j + 16 <= ne) {
#pragma unroll
                for (int k = 0; k < 16; ++k) {
                    const int jj = j + k;
                    if ((jj & 63) == 0 && jj != 0) {
                        colv0 = colv1;
                        ++bidx;
                        int ad = S + (bidx + 1) * 64 + lane;
                        colv1 = (ad < S + ne) ? cols[ad] : 0;
                    }
                    while (jj == bnd) finalize();
                    acc += __uint_as_float(ubuf[k] << 16);
                    int ec = min(jj + 16, ne - 1);
                    int src = ((ec >> 6) == bidx) ? colv0 : colv1;
                    int cc = rlanei(src, ec & 63);
                    ubuf[k] = Ml[(size_t)cc * 64];
                }
                j += 16;
            }
            for (; j < ne; ++j) {
                while (j == bnd) finalize();
                acc += __uint_as_float(ubuf[j & 15] << 16);
            }
        }
        while (node < CHUNK) finalize();
        flush();
    }
}

// ---- assemble fused vector: [mean | max | relu(meta@Wm+bm) | emb | pad] ----
__global__ __launch_bounds__(256) void k_asm(
        const float* __restrict__ psum, const float* __restrict__ pmax,
        const int* __restrict__ gstart, const float* __restrict__ metadata,
        const int* __restrict__ species, const float* __restrict__ emb,
        const float* __restrict__ Wm, const float* __restrict__ bm,
        float* __restrict__ fused, int G) {
    const int lane = threadIdx.x & 63;
    int wv = (blockIdx.x * blockDim.x + threadIdx.x) >> 6;
    const int nw = (gridDim.x * blockDim.x) >> 6;
    const float bmr = bm[lane];
    float wmr[16];
#pragma unroll
    for (int k = 0; k < 16; ++k) wmr[k] = Wm[k * 64 + lane];
    for (int g = wv; g < G; g += nw) {
        float gc = (float)(gstart[g + 1] - gstart[g]);
        float mean = psum[(size_t)g * 64 + lane] / fmaxf(gc, 1.0f);
        float mx = pmax[(size_t)g * 64 + lane];
        float md = lane < 16 ? metadata[(size_t)g * 16 + lane] : 0.0f;
        float mval = bmr;
#pragma unroll
        for (int k = 0; k < 16; ++k) mval = fmaf(rlane(md, k), wmr[k], mval);
        mval = fmaxf(mval, 0.0f);
        const int sid = species[g];
        float* fr = fused + (size_t)g * 224;
        fr[lane] = mean;
        fr[64 + lane] = mx;
        fr[128 + lane] = mval;
        if (lane < 16) fr[192 + lane] = emb[(size_t)sid * 16 + lane];
        else if (lane < 32) fr[192 + lane] = 0.0f;
    }
}

// ---- MFMA predictor head ----
__global__ __launch_bounds__(256, 2) void k_pred_mfma(
        const float* __restrict__ fused, const float* __restrict__ Wp1,
        const float* __restrict__ bp1, const float* __restrict__ Wp2,
        const float* __restrict__ bp2, float* __restrict__ out, int G) {
    __shared__ __align__(16) short Whi[64 * 232];
    __shared__ __align__(16) short Wlo[64 * 232];
    const int t = threadIdx.x;
    for (int idx = t; idx < 64 * 232; idx += 256) {
        int n = idx / 232;
        int k = idx % 232;
        float w = (k < 208) ? Wp1[(size_t)k * 64 + n] : 0.0f;
        short hi = f2bf(w);
        Whi[n * 232 + k] = hi;
        Wlo[n * 232 + k] = f2bf(w - bf2f(hi));
    }
    __syncthreads();

    const int lane = t & 63;
    const int wave = t >> 6;
    const int m = lane & 15;
    const int q = lane >> 4;
    const int g0 = (blockIdx.x * 4 + wave) * 16;
    if (g0 >= G) return;

    const float* rowp = fused + (size_t)(g0 + m) * 224 + q * 8;

    f32x4 C[4];
#pragma unroll
    for (int nt = 0; nt < 4; ++nt) C[nt] = (f32x4){0.f, 0.f, 0.f, 0.f};

#pragma unroll
    for (int kt = 0; kt < 7; ++kt) {
        f32x4 a0 = *(const f32x4*)(rowp + kt * 32);
        f32x4 a1 = *(const f32x4*)(rowp + kt * 32 + 4);
        bf16x8 Ahi, Alo;
#pragma unroll
        for (int j = 0; j < 4; ++j) {
            short hi = f2bf(a0[j]);
            Ahi[j] = hi;
            Alo[j] = f2bf(a0[j] - bf2f(hi));
        }
#pragma unroll
        for (int j = 0; j < 4; ++j) {
            short hi = f2bf(a1[j]);
            Ahi[4 + j] = hi;
            Alo[4 + j] = f2bf(a1[j] - bf2f(hi));
        }
#pragma unroll
        for (int nt = 0; nt < 4; ++nt) {
            const int boff = (nt * 16 + m) * 232 + kt * 32 + q * 8;
            bf16x8 Bh = *(const bf16x8*)&Whi[boff];
            bf16x8 Bl = *(const bf16x8*)&Wlo[boff];
            C[nt] = __builtin_amdgcn_mfma_f32_16x16x32_bf16(Ahi, Bh, C[nt], 0, 0, 0);
            C[nt] = __builtin_amdgcn_mfma_f32_16x16x32_bf16(Ahi, Bl, C[nt], 0, 0, 0);
            C[nt] = __builtin_amdgcn_mfma_f32_16x16x32_bf16(Alo, Bh, C[nt], 0, 0, 0);
        }
    }

    float wp2r[4], bp1r[4];
#pragma unroll
    for (int nt = 0; nt < 4; ++nt) {
        wp2r[nt] = Wp2[nt * 16 + m];
        bp1r[nt] = bp1[nt * 16 + m];
    }
    const float bp2v = bp2[0];
    float s[4];
#pragma unroll
    for (int r = 0; r < 4; ++r) {
        float acc = 0.0f;
#pragma unroll
        for (int nt = 0; nt < 4; ++nt)
            acc += fmaxf(C[nt][r] + bp1r[nt], 0.0f) * wp2r[nt];
        s[r] = acc;
    }
#pragma unroll
    for (int off = 1; off < 16; off <<= 1) {
#pragma unroll
        for (int r = 0; r < 4; ++r) s[r] += __shfl_xor(s[r], off);
    }
    if (m == 0) {
#pragma unroll
        for (int r = 0; r < 4; ++r) out[g0 + q * 4 + r] = s[r] + bp2v;
    }
}

extern "C" void kernel_launch(void* const* d_in, const int* in_sizes, int n_in,
                              void* d_out, int out_size, void* d_ws, size_t ws_size,
                              hipStream_t stream) {
    const int N = N_NODES, E = N_EDGES, G = N_GRAPHS;

    const float* x        = (const float*)d_in[0];
    const float* metadata = (const float*)d_in[1];
    const int*   ei       = (const int*)d_in[2];
    const int*   batch    = (const int*)d_in[3];
    const int*   species  = (const int*)d_in[4];
    const float* W1 = (const float*)d_in[5];
    const float* b1 = (const float*)d_in[6];
    const float* W2 = (const float*)d_in[7];
    const float* b2 = (const float*)d_in[8];
    const float* W3 = (const float*)d_in[9];
    const float* b3 = (const float*)d_in[10];
    const float* Wm = (const float*)d_in[11];
    const float* bm = (const float*)d_in[12];
    const float* emb = (const float*)d_in[13];
    const float* Wp1 = (const float*)d_in[14];
    const float* bp1 = (const float*)d_in[15];
    const float* Wp2 = (const float*)d_in[16];
    const float* bp2 = (const float*)d_in[17];
    float* out = (float*)d_out;

    char* ws = (char*)d_ws;
    size_t off = 0;
    auto alloc = [&](size_t bytes) -> void* {
        void* p = ws + off;
        off = (off + bytes + 255) & ~(size_t)255;
        return p;
    };
    int*   row_ptr = (int*)alloc((size_t)(N + 1) * 4);
    float* dinv    = (float*)alloc((size_t)N * 4);
    int*   gstart  = (int*)alloc((size_t)(G + 1) * 4);
    // ---- contiguous zero region: bkt | bcur | psum | pmax (single memset) ----
    size_t z0 = off;
    int*   bkt     = (int*)alloc((size_t)NBKT * 4);
    int*   bcur    = (int*)alloc((size_t)NBKT * 4);
    float* psum    = (float*)alloc((size_t)G * 64 * 4);
    float* pmax    = (float*)alloc((size_t)G * 64 * 4);
    size_t zlen = off - z0;
    // -------------------------------------------------------------------------
    int*   colsS   = (int*)alloc((size_t)E * 4);
    bfu*   Mb      = (bfu*)alloc((size_t)N * 64 * 2);    // bf16 GEMM output
    bfu*   hb      = (bfu*)alloc((size_t)N * 64 * 2);    // bf16 h' (agg output)
    float* fused   = (float*)alloc((size_t)G * 224 * 4);

    int2* tmp = (int2*)Mb;        // aliases Mb: dead until layer-1 GEMM writes it

    hipMemsetAsync(ws + z0, 0, zlen, stream);

    const int nbGb = (N + 256) / 256 + 1;                // 1563 >= NBBIN(391)
    k_bcnt_gb<<<nbGb, 256, 0, stream>>>(ei, bkt, batch, gstart, N, G, E);
    k_bin<<<NBBIN, 256, 0, stream>>>(ei, ei + E, bkt, bcur, tmp, E);
    k_csr<<<NBKT, 256, 0, stream>>>(tmp, bkt, row_ptr, dinv, colsS, N, E);

    const int nTiles = N / 16;          // 25000
    const int nbAgg = NCHUNK / 4;       // 2000 blocks = 8000 waves = NCHUNK
    const int nbGemm = 1024;            // 4 blocks/CU resident, one generation
    // layer 1: M1 = (Dinv x) @ W1 (bf16) ; agg -> h1' bf16
    k_gemm_mfma<32, true, false><<<nbGemm, 256, 0, stream>>>(x, W1, dinv, Mb, nTiles);
    k_agg_seg<0><<<nbAgg, 256, 0, stream>>>(Mb, b1, row_ptr, colsS, dinv, batch,
                                            hb, psum, pmax);
    // layer 2 (A bf16)
    k_gemm_mfma<64, false, true><<<nbGemm, 256, 0, stream>>>(hb, W2, dinv, Mb, nTiles);
    k_agg_seg<0><<<nbAgg, 256, 0, stream>>>(Mb, b2, row_ptr, colsS, dinv, batch,
                                            hb, psum, pmax);
    // layer 3: GEMM (A bf16) then agg+pool (atomics into psum/pmax)
    k_gemm_mfma<64, false, true><<<nbGemm, 256, 0, stream>>>(hb, W3, dinv, Mb, nTiles);
    k_agg_seg<1><<<nbAgg, 256, 0, stream>>>(Mb, b3, row_ptr, colsS, dinv, batch,
                                            hb, psum, pmax);

    k_asm<<<512, 256, 0, stream>>>(psum, pmax, gstart, metadata, species, emb, Wm, bm,
                                   fused, G);
    k_pred_mfma<<<(G / 16 + 3) / 4, 256, 0, stream>>>(fused, Wp1, bp1, Wp2, bp2, out, G);
}